// Round 1
// baseline (1763.124 us; speedup 1.0000x reference)
//
#include <hip/hip_runtime.h>
#include <cstdint>

#define NN 50000
#define NE 800000
static constexpr int HD = 128;     // H*D for every layer
static constexpr int FIN = 128;    // input feature dim for every layer
static constexpr int EF_DIM = 16;  // edge feature dim
static constexpr int BN = 16;      // nodes per block in feat GEMM

// ---- monotone float<->uint encoding for atomicMax on float ----
__device__ __forceinline__ unsigned enc_f(float f) {
    unsigned u = __float_as_uint(f);
    return (u & 0x80000000u) ? ~u : (u | 0x80000000u);
}
__device__ __forceinline__ float dec_f(unsigned u) {
    unsigned v = (u & 0x80000000u) ? (u & 0x7fffffffu) : ~u;
    return __uint_as_float(v);
}
// enc(-inf) = ~0xFF800000 = 0x007FFFFF
#define ENC_NEG_INF 0x007FFFFFu

// ---- feat = X @ W  (X:[NN,FIN], W:[FIN,HD] -> F:[NN,HD]) ----
__global__ __launch_bounds__(128) void k_feat(const float* __restrict__ X,
                                              const float* __restrict__ W,
                                              float* __restrict__ F) {
    __shared__ float sX[BN][FIN];
    const int t = threadIdx.x;               // 0..127 -> output column
    const int nbase = blockIdx.x * BN;
    for (int i = t; i < BN * FIN; i += 128) {
        int r = i >> 7, c = i & 127;
        int n = nbase + r;
        sX[r][c] = (n < NN) ? X[n * FIN + c] : 0.f;
    }
    __syncthreads();
    float acc[BN];
#pragma unroll
    for (int i = 0; i < BN; i++) acc[i] = 0.f;
    for (int f = 0; f < FIN; f++) {
        float w = W[f * HD + t];
#pragma unroll
        for (int i = 0; i < BN; i++) acc[i] += sX[i][f] * w;
    }
#pragma unroll
    for (int i = 0; i < BN; i++) {
        int n = nbase + i;
        if (n < NN) F[n * HD + t] = acc[i];
    }
}

// ---- el[n,h] = <feat[n,h,:], al[h,:]> ; er likewise ----
__global__ void k_elr(const float* __restrict__ F, const float* __restrict__ al,
                      const float* __restrict__ ar, float* __restrict__ el,
                      float* __restrict__ er, int H, int D) {
    int idx = blockIdx.x * blockDim.x + threadIdx.x;  // n*H + h
    if (idx >= NN * H) return;
    int n = idx / H, h = idx % H;
    const float* fr = F + n * HD + h * D;
    const float* alr = al + h * D;
    const float* arr = ar + h * D;
    float sl = 0.f, sr = 0.f;
    for (int d = 0; d < D; d++) {
        float v = fr[d];
        sl += v * alr[d];
        sr += v * arr[d];
    }
    el[idx] = sl;
    er[idx] = sr;
}

// ---- M[f,h] = sum_d We[f, h*D+d] * ae[h,d]   (folds ef@We with ae) ----
__global__ void k_M(const float* __restrict__ We, const float* __restrict__ ae,
                    float* __restrict__ M, int H, int D) {
    int idx = threadIdx.x;  // f*H + h
    if (idx >= EF_DIM * H) return;
    int f = idx / H, h = idx % H;
    float s = 0.f;
    for (int d = 0; d < D; d++) s += We[f * HD + h * D + d] * ae[h * D + d];
    M[f * H + h] = s;
}

// ---- init emax/esum per (node,head) ----
__global__ void k_fill_nh(unsigned* __restrict__ emax, float* __restrict__ esum, int NH) {
    int i = blockIdx.x * blockDim.x + threadIdx.x;
    if (i < NH) { emax[i] = ENC_NEG_INF; esum[i] = 0.f; }
}

// ---- edge scores: leaky_relu(el[src]+er[dst]+ef@M), atomic max into emax ----
__global__ void k_score(const float* __restrict__ EFt, const int* __restrict__ src,
                        const int* __restrict__ dst, const float* __restrict__ el,
                        const float* __restrict__ er, const float* __restrict__ M,
                        float* __restrict__ esc, unsigned* __restrict__ emax, int H) {
    __shared__ float sM[EF_DIM * 4];
    int t = threadIdx.x;
    if (t < EF_DIM * H) sM[t] = M[t];
    __syncthreads();
    int e = blockIdx.x * blockDim.x + t;
    if (e >= NE) return;
    float ef[EF_DIM];
    const float4* efp = (const float4*)(EFt + e * EF_DIM);
#pragma unroll
    for (int q = 0; q < 4; q++) {
        float4 v = efp[q];
        ef[4 * q] = v.x; ef[4 * q + 1] = v.y; ef[4 * q + 2] = v.z; ef[4 * q + 3] = v.w;
    }
    int s = src[e], d = dst[e];
    for (int h = 0; h < H; h++) {
        float ee = 0.f;
#pragma unroll
        for (int f = 0; f < EF_DIM; f++) ee += ef[f] * sM[f * H + h];
        float x = el[s * H + h] + er[d * H + h] + ee;
        x = (x > 0.f) ? x : 0.2f * x;
        esc[e * H + h] = x;
        atomicMax(&emax[d * H + h], enc_f(x));
    }
}

// ---- ex = exp(e - emax[dst]) ; esum[dst] += ex ----
__global__ void k_exp(const int* __restrict__ dst, float* __restrict__ esc,
                      const unsigned* __restrict__ emax, float* __restrict__ esum, int H) {
    int i = blockIdx.x * blockDim.x + threadIdx.x;  // e*H + h
    if (i >= NE * H) return;
    int e = i / H, h = i % H;
    int d = dst[e];
    float m = dec_f(emax[d * H + h]);
    float ex = __expf(esc[i] - m);
    esc[i] = ex;
    atomicAdd(&esum[d * H + h], ex);
}

// ---- rst = bias (broadcast) ----
__global__ void k_init_rst(float* __restrict__ R, const float* __restrict__ b, int total) {
    int i = blockIdx.x * blockDim.x + threadIdx.x;
    if (i < total) R[i] = b[i & 127];
}

// ---- rst[dst] += feat[src] * (ex/esum[dst]) ----
__global__ void k_agg(const int* __restrict__ src, const int* __restrict__ dst,
                      const float* __restrict__ F, const float* __restrict__ esc,
                      const float* __restrict__ esum, float* __restrict__ R, int H, int D) {
    int i = blockIdx.x * blockDim.x + threadIdx.x;  // e*128 + c
    if (i >= NE * HD) return;
    int e = i >> 7;
    int c = i & 127;
    int h = c / D;
    int s = src[e], d = dst[e];
    float a = esc[e * H + h] / esum[d * H + h];
    atomicAdd(&R[d * HD + c], F[s * HD + c] * a);
}

// ---- in-place relu ----
__global__ void k_relu(float* __restrict__ R, int total) {
    int i = blockIdx.x * blockDim.x + threadIdx.x;
    if (i < total) R[i] = fmaxf(R[i], 0.f);
}

static void run_layer(const float* X, const float* EFt, const int* src, const int* dst,
                      const float* W, const float* We, const float* al, const float* ar,
                      const float* ae, const float* b, int H, int D, bool act,
                      float* featbuf, float* esc, float* el, float* er, unsigned* emax,
                      float* esum, float* M, float* out, hipStream_t stream) {
    const int NH = NN * H;
    hipLaunchKernelGGL(k_feat, dim3((NN + BN - 1) / BN), dim3(128), 0, stream, X, W, featbuf);
    hipLaunchKernelGGL(k_elr, dim3((NH + 255) / 256), dim3(256), 0, stream,
                       featbuf, al, ar, el, er, H, D);
    hipLaunchKernelGGL(k_M, dim3(1), dim3(64), 0, stream, We, ae, M, H, D);
    hipLaunchKernelGGL(k_fill_nh, dim3((NH + 255) / 256), dim3(256), 0, stream, emax, esum, NH);
    hipLaunchKernelGGL(k_score, dim3((NE + 255) / 256), dim3(256), 0, stream,
                       EFt, src, dst, el, er, M, esc, emax, H);
    hipLaunchKernelGGL(k_exp, dim3((NE * H + 255) / 256), dim3(256), 0, stream,
                       dst, esc, emax, esum, H);
    hipLaunchKernelGGL(k_init_rst, dim3((NN * HD + 255) / 256), dim3(256), 0, stream,
                       out, b, NN * HD);
    hipLaunchKernelGGL(k_agg, dim3((NE * HD + 255) / 256), dim3(256), 0, stream,
                       src, dst, featbuf, esc, esum, out, H, D);
    if (act)
        hipLaunchKernelGGL(k_relu, dim3((NN * HD + 255) / 256), dim3(256), 0, stream,
                           out, NN * HD);
}

extern "C" void kernel_launch(void* const* d_in, const int* in_sizes, int n_in,
                              void* d_out, int out_size, void* d_ws, size_t ws_size,
                              hipStream_t stream) {
    const float* h   = (const float*)d_in[0];
    const float* eft = (const float*)d_in[1];
    const int* src   = (const int*)d_in[2];
    const int* dst   = (const int*)d_in[3];
    auto P = [&](int i) { return (const float*)d_in[i]; };

    float* ws = (float*)d_ws;
    float* featbuf = ws;                       // 6.4M floats
    float* bufA    = featbuf + (size_t)NN * HD;
    float* bufB    = bufA + (size_t)NN * HD;
    float* esc     = bufB + (size_t)NN * HD;   // NE*4 = 3.2M floats
    float* el      = esc + (size_t)NE * 4;
    float* er      = el + (size_t)NN * 4;
    float* esum    = er + (size_t)NN * 4;
    unsigned* emax = (unsigned*)(esum + (size_t)NN * 4);
    float* M       = (float*)(emax + (size_t)NN * 4);
    float* out     = (float*)d_out;

    // layer 0: h -> bufA (H=4, D=32, relu)
    run_layer(h, eft, src, dst, P(4), P(5), P(6), P(7), P(8), P(9), 4, 32, true,
              featbuf, esc, el, er, emax, esum, M, bufA, stream);
    // layer 1: bufA -> bufB (H=4, D=32, relu)
    run_layer(bufA, eft, src, dst, P(10), P(11), P(12), P(13), P(14), P(15), 4, 32, true,
              featbuf, esc, el, er, emax, esum, M, bufB, stream);
    // layer 2: bufB -> out (H=1, D=128, no act)
    run_layer(bufB, eft, src, dst, P(16), P(17), P(18), P(19), P(20), P(21), 1, 128, false,
              featbuf, esc, el, er, emax, esum, M, out, stream);
}

// Round 2
// 740.521 us; speedup vs baseline: 2.3809x; 2.3809x over previous
//
#include <hip/hip_runtime.h>
#include <cstdint>

#define NN 50000
#define NE 800000
static constexpr int HD = 128;     // H*D for every layer
static constexpr int FIN = 128;    // input feature dim for every layer
static constexpr int EF_DIM = 16;  // edge feature dim
static constexpr int BN = 16;      // nodes per block in feat GEMM
static constexpr int CH = 256;     // edge chunk per node in fused agg

// ============================ CSR build (once) ============================

__global__ void k_zero_int(int* __restrict__ p, int n) {
    int i = blockIdx.x * blockDim.x + threadIdx.x;
    if (i < n) p[i] = 0;
}

__global__ void k_hist(const int* __restrict__ dst, int* __restrict__ deg) {
    int e = blockIdx.x * blockDim.x + threadIdx.x;
    if (e < NE) atomicAdd(&deg[dst[e]], 1);
}

// one block of 1024 threads: exclusive scan of deg[NN] -> row_ptr[NN+1], cursor copy
__global__ __launch_bounds__(1024) void k_scan(const int* __restrict__ deg,
                                               int* __restrict__ row_ptr,
                                               int* __restrict__ cursor) {
    __shared__ int s[1024];
    const int t = threadIdx.x;
    const int chunk = (NN + 1023) / 1024;  // 49
    const int lo = t * chunk;
    const int hi = min(lo + chunk, NN);
    int sum = 0;
    for (int i = lo; i < hi; i++) sum += deg[i];
    s[t] = sum;
    __syncthreads();
    // Hillis-Steele inclusive scan
    for (int off = 1; off < 1024; off <<= 1) {
        int v = (t >= off) ? s[t - off] : 0;
        __syncthreads();
        s[t] += v;
        __syncthreads();
    }
    int running = s[t] - sum;  // exclusive offset for this thread's chunk
    for (int i = lo; i < hi; i++) {
        row_ptr[i] = running;
        cursor[i] = running;
        running += deg[i];
    }
    if (t == 1023) row_ptr[NN] = NE;
}

__global__ void k_scatter(const int* __restrict__ src, const int* __restrict__ dst,
                          int* __restrict__ cursor, int* __restrict__ eperm,
                          int* __restrict__ ssrc, int* __restrict__ sdst) {
    int e = blockIdx.x * blockDim.x + threadIdx.x;
    if (e >= NE) return;
    int d = dst[e];
    int pos = atomicAdd(&cursor[d], 1);
    eperm[pos] = e;
    ssrc[pos] = src[e];
    sdst[pos] = d;
}

// ============================ per-layer kernels ============================

// feat = X @ W  (X:[NN,FIN], W:[FIN,HD] -> F:[NN,HD])
__global__ __launch_bounds__(128) void k_feat(const float* __restrict__ X,
                                              const float* __restrict__ W,
                                              float* __restrict__ F) {
    __shared__ float sX[BN][FIN];
    const int t = threadIdx.x;               // 0..127 -> output column
    const int nbase = blockIdx.x * BN;
    for (int i = t; i < BN * FIN; i += 128) {
        int r = i >> 7, c = i & 127;
        int n = nbase + r;
        sX[r][c] = (n < NN) ? X[n * FIN + c] : 0.f;
    }
    __syncthreads();
    float acc[BN];
#pragma unroll
    for (int i = 0; i < BN; i++) acc[i] = 0.f;
    for (int f = 0; f < FIN; f++) {
        float w = W[f * HD + t];
#pragma unroll
        for (int i = 0; i < BN; i++) acc[i] += sX[i][f] * w;
    }
#pragma unroll
    for (int i = 0; i < BN; i++) {
        int n = nbase + i;
        if (n < NN) F[n * HD + t] = acc[i];
    }
}

// el[n,h] = <feat[n,h,:], al[h,:]> ; er likewise
__global__ void k_elr(const float* __restrict__ F, const float* __restrict__ al,
                      const float* __restrict__ ar, float* __restrict__ el,
                      float* __restrict__ er, int H, int D) {
    int idx = blockIdx.x * blockDim.x + threadIdx.x;  // n*H + h
    if (idx >= NN * H) return;
    int n = idx / H, h = idx % H;
    const float* fr = F + n * HD + h * D;
    const float* alr = al + h * D;
    const float* arr = ar + h * D;
    float sl = 0.f, sr = 0.f;
    for (int d = 0; d < D; d++) {
        float v = fr[d];
        sl += v * alr[d];
        sr += v * arr[d];
    }
    el[idx] = sl;
    er[idx] = sr;
}

// M[f,h] = sum_d We[f, h*D+d] * ae[h,d]   (folds ef@We with ae)
__global__ void k_M(const float* __restrict__ We, const float* __restrict__ ae,
                    float* __restrict__ M, int H, int D) {
    int idx = threadIdx.x;  // f*H + h
    if (idx >= EF_DIM * H) return;
    int f = idx / H, h = idx % H;
    float s = 0.f;
    for (int d = 0; d < D; d++) s += We[f * HD + h * D + d] * ae[h * D + d];
    M[f * H + h] = s;
}

// scores in dst-sorted edge order: esc[i*H+h] = leaky(el[ssrc[i]]+er[sdst[i]]+EF[eperm[i]]@M)
__global__ void k_score(const float* __restrict__ EFt, const int* __restrict__ eperm,
                        const int* __restrict__ ssrc, const int* __restrict__ sdst,
                        const float* __restrict__ el, const float* __restrict__ er,
                        const float* __restrict__ M, float* __restrict__ esc, int H) {
    __shared__ float sM[EF_DIM * 4];
    int t = threadIdx.x;
    if (t < EF_DIM * H) sM[t] = M[t];
    __syncthreads();
    int i = blockIdx.x * blockDim.x + t;
    if (i >= NE) return;
    int e = eperm[i];
    float ef[EF_DIM];
    const float4* efp = (const float4*)(EFt + (size_t)e * EF_DIM);
#pragma unroll
    for (int q = 0; q < 4; q++) {
        float4 v = efp[q];
        ef[4 * q] = v.x; ef[4 * q + 1] = v.y; ef[4 * q + 2] = v.z; ef[4 * q + 3] = v.w;
    }
    int s = ssrc[i], d = sdst[i];
    for (int h = 0; h < H; h++) {
        float ee = 0.f;
#pragma unroll
        for (int f = 0; f < EF_DIM; f++) ee += ef[f] * sM[f * H + h];
        float x = el[s * H + h] + er[d * H + h] + ee;
        x = (x > 0.f) ? x : 0.2f * x;
        esc[(size_t)i * H + h] = x;
    }
}

// fused per-dst-node: softmax over incoming edges + weighted aggregation + bias (+relu)
// one block (128 threads) per node
__global__ __launch_bounds__(128) void k_node(const int* __restrict__ row_ptr,
                                              const int* __restrict__ ssrc,
                                              const float* __restrict__ esc,
                                              const float* __restrict__ F,
                                              const float* __restrict__ b,
                                              float* __restrict__ R,
                                              int H, int D, int act) {
    __shared__ float red[128];
    __shared__ float smax[4];
    __shared__ float sinv[4];
    __shared__ float wlds[CH * 4];

    const int n = blockIdx.x;
    const int t = threadIdx.x;
    const int start = row_ptr[n];
    const int end = row_ptr[n + 1];
    const int h_t = t % H;  // constant per thread since 128 % H == 0

    if (start == end) {
        float v = b[t];
        if (act) v = fmaxf(v, 0.f);
        R[(size_t)n * HD + t] = v;
        return;
    }

    // ---- max per head ----
    float pmax = -3.0e38f;
    for (int j = start * H + t; j < end * H; j += 128) pmax = fmaxf(pmax, esc[j]);
    red[t] = pmax;
    __syncthreads();
    for (int s = 64; s >= H; s >>= 1) {
        if (t < s) red[t] = fmaxf(red[t], red[t + s]);
        __syncthreads();
    }
    if (t < H) smax[t] = red[t];
    __syncthreads();

    // ---- sum of exp per head ----
    float m_t = smax[h_t];
    float psum = 0.f;
    for (int j = start * H + t; j < end * H; j += 128) psum += __expf(esc[j] - m_t);
    red[t] = psum;
    __syncthreads();
    for (int s = 64; s >= H; s >>= 1) {
        if (t < s) red[t] += red[t + s];
        __syncthreads();
    }
    if (t < H) sinv[t] = 1.f / red[t];
    __syncthreads();

    // ---- aggregate: acc[c] = sum_i w[i,h(c)] * F[ssrc[i], c] ----
    const int c = t;
    const int h_c = c / D;
    const float m_c = smax[h_c];
    const float inv_c = sinv[h_c];
    float acc = 0.f;
    for (int base = start; base < end; base += CH) {
        int cnt = min(CH, end - base);
        int elems = cnt * H;
        for (int j = t; j < elems; j += 128)
            wlds[j] = __expf(esc[(size_t)base * H + j] - smax[j % H]);
        __syncthreads();
        for (int i = 0; i < cnt; i++) {
            int sn = ssrc[base + i];
            acc += F[(size_t)sn * HD + c] * wlds[i * H + h_c];
        }
        __syncthreads();
    }
    float v = acc * inv_c + b[c];
    if (act) v = fmaxf(v, 0.f);
    R[(size_t)n * HD + c] = v;
    (void)m_c;
}

// ============================ driver ============================

static void run_layer(const float* X, const float* EFt, const int* eperm,
                      const int* ssrc, const int* sdst, const int* row_ptr,
                      const float* W, const float* We, const float* al, const float* ar,
                      const float* ae, const float* b, int H, int D, int act,
                      float* featbuf, float* esc, float* el, float* er, float* M,
                      float* out, hipStream_t stream) {
    const int NH = NN * H;
    hipLaunchKernelGGL(k_feat, dim3((NN + BN - 1) / BN), dim3(128), 0, stream, X, W, featbuf);
    hipLaunchKernelGGL(k_elr, dim3((NH + 255) / 256), dim3(256), 0, stream,
                       featbuf, al, ar, el, er, H, D);
    hipLaunchKernelGGL(k_M, dim3(1), dim3(64), 0, stream, We, ae, M, H, D);
    hipLaunchKernelGGL(k_score, dim3((NE + 255) / 256), dim3(256), 0, stream,
                       EFt, eperm, ssrc, sdst, el, er, M, esc, H);
    hipLaunchKernelGGL(k_node, dim3(NN), dim3(128), 0, stream,
                       row_ptr, ssrc, esc, featbuf, b, out, H, D, act);
}

extern "C" void kernel_launch(void* const* d_in, const int* in_sizes, int n_in,
                              void* d_out, int out_size, void* d_ws, size_t ws_size,
                              hipStream_t stream) {
    const float* h   = (const float*)d_in[0];
    const float* eft = (const float*)d_in[1];
    const int* src   = (const int*)d_in[2];
    const int* dst   = (const int*)d_in[3];
    auto P = [&](int i) { return (const float*)d_in[i]; };

    float* ws = (float*)d_ws;
    float* featbuf = ws;                            // 6.4M floats
    float* bufA    = featbuf + (size_t)NN * HD;     // 6.4M
    float* esc     = bufA + (size_t)NN * HD;        // 3.2M
    float* el      = esc + (size_t)NE * 4;          // 0.2M
    float* er      = el + (size_t)NN * 4;           // 0.2M
    float* M       = er + (size_t)NN * 4;           // 64
    int* row_ptr   = (int*)(M + 64);                // NN+1
    int* cursor    = row_ptr + (NN + 1);            // NN
    int* eperm     = cursor + NN;                   // NE
    int* ssrc      = eperm + NE;                    // NE
    int* sdst      = ssrc + NE;                     // NE
    float* out     = (float*)d_out;

    // ---- build CSR by dst (once; graph shared by all 3 layers) ----
    hipLaunchKernelGGL(k_zero_int, dim3((NN + 255) / 256), dim3(256), 0, stream, cursor, NN);
    hipLaunchKernelGGL(k_hist, dim3((NE + 255) / 256), dim3(256), 0, stream, dst, cursor);
    hipLaunchKernelGGL(k_scan, dim3(1), dim3(1024), 0, stream, cursor, row_ptr, cursor);
    // NOTE: k_scan reads deg from `cursor` then overwrites cursor with row starts:
    // safe because each thread reads deg[i] before writing cursor[i] in same loop? No —
    // it reads all its chunk first (sum), then writes. Within one thread same range: read
    // pass completes before write pass for that thread's own range only. Other threads
    // never touch this range. So safe.
    hipLaunchKernelGGL(k_scatter, dim3((NE + 255) / 256), dim3(256), 0, stream,
                       src, dst, cursor, eperm, ssrc, sdst);

    // layer 0: h -> bufA (H=4, D=32, relu)
    run_layer(h, eft, eperm, ssrc, sdst, row_ptr, P(4), P(5), P(6), P(7), P(8), P(9),
              4, 32, 1, featbuf, esc, el, er, M, bufA, stream);
    // layer 1: bufA -> bufA (in-place safe: bufA only read by k_feat, first kernel)
    run_layer(bufA, eft, eperm, ssrc, sdst, row_ptr, P(10), P(11), P(12), P(13), P(14), P(15),
              4, 32, 1, featbuf, esc, el, er, M, bufA, stream);
    // layer 2: bufA -> out (H=1, D=128, no act)
    run_layer(bufA, eft, eperm, ssrc, sdst, row_ptr, P(16), P(17), P(18), P(19), P(20), P(21),
              1, 128, 0, featbuf, esc, el, er, M, out, stream);
}

// Round 3
// 531.537 us; speedup vs baseline: 3.3170x; 1.3932x over previous
//
#include <hip/hip_runtime.h>
#include <cstdint>

#define NN 50000
#define NE 800000
static constexpr int HD = 128;     // H*D for every layer
static constexpr int FIN = 128;    // input feature dim for every layer
static constexpr int EF_DIM = 16;  // edge feature dim
static constexpr int BN = 16;      // nodes per block in feat GEMM
static constexpr int SCAN_B = 256;
static constexpr int NPARTS = (NN + SCAN_B - 1) / SCAN_B;  // 196

// ============================ CSR build (once) ============================

__global__ void k_hist(const int* __restrict__ dst, int* __restrict__ deg) {
    int e = blockIdx.x * blockDim.x + threadIdx.x;
    if (e < NE) atomicAdd(&deg[dst[e]], 1);
}

// per-block sums of deg -> part[NPARTS]
__global__ __launch_bounds__(SCAN_B) void k_part(const int* __restrict__ deg,
                                                 int* __restrict__ part) {
    __shared__ int s[SCAN_B];
    int t = threadIdx.x;
    int i = blockIdx.x * SCAN_B + t;
    s[t] = (i < NN) ? deg[i] : 0;
    __syncthreads();
    for (int off = SCAN_B / 2; off > 0; off >>= 1) {
        if (t < off) s[t] += s[t + off];
        __syncthreads();
    }
    if (t == 0) part[blockIdx.x] = s[0];
}

// exclusive scan of part[NPARTS] in one small block
__global__ __launch_bounds__(SCAN_B) void k_scanpart(int* __restrict__ part) {
    __shared__ int s[SCAN_B];
    int t = threadIdx.x;
    int v = (t < NPARTS) ? part[t] : 0;
    s[t] = v;
    __syncthreads();
    for (int off = 1; off < SCAN_B; off <<= 1) {
        int u = (t >= off) ? s[t - off] : 0;
        __syncthreads();
        s[t] += u;
        __syncthreads();
    }
    if (t < NPARTS) part[t] = s[t] - v;  // exclusive
}

// block-local exclusive scan + part offset -> row_ptr, cursor
__global__ __launch_bounds__(SCAN_B) void k_rowptr(const int* __restrict__ deg,
                                                   const int* __restrict__ part,
                                                   int* __restrict__ row_ptr,
                                                   int* __restrict__ cursor) {
    __shared__ int s[SCAN_B];
    int t = threadIdx.x;
    int i = blockIdx.x * SCAN_B + t;
    int v = (i < NN) ? deg[i] : 0;
    s[t] = v;
    __syncthreads();
    for (int off = 1; off < SCAN_B; off <<= 1) {
        int u = (t >= off) ? s[t - off] : 0;
        __syncthreads();
        s[t] += u;
        __syncthreads();
    }
    int excl = s[t] - v + part[blockIdx.x];
    if (i < NN) { row_ptr[i] = excl; cursor[i] = excl; }
    if (i == NN) row_ptr[NN] = NE;
}

__global__ void k_scatter(const int* __restrict__ src, const int* __restrict__ dst,
                          int* __restrict__ cursor, int* __restrict__ eperm,
                          int* __restrict__ ssrc, int* __restrict__ sdst) {
    int e = blockIdx.x * blockDim.x + threadIdx.x;
    if (e >= NE) return;
    int d = dst[e];
    int pos = atomicAdd(&cursor[d], 1);
    eperm[pos] = e;
    ssrc[pos] = src[e];
    sdst[pos] = d;
}

// M[f,h] = sum_d We[f, h*D+d] * ae[h,d] for all three layers in one launch
__global__ void k_M3(const float* __restrict__ We0, const float* __restrict__ ae0,
                     const float* __restrict__ We1, const float* __restrict__ ae1,
                     const float* __restrict__ We2, const float* __restrict__ ae2,
                     float* __restrict__ M) {
    int l = blockIdx.x;
    int t = threadIdx.x;
    const float* We = (l == 0) ? We0 : (l == 1) ? We1 : We2;
    const float* ae = (l == 0) ? ae0 : (l == 1) ? ae1 : ae2;
    int H = (l == 2) ? 1 : 4;
    int D = (l == 2) ? 128 : 32;
    if (t >= EF_DIM * H) return;
    int f = t / H, h = t % H;
    float s = 0.f;
    for (int d = 0; d < D; d++) s += We[f * HD + h * D + d] * ae[h * D + d];
    M[l * 64 + f * H + h] = s;
}

// ============================ per-layer kernels ============================

// feat = X @ W  (X:[NN,FIN], W:[FIN,HD] -> F:[NN,HD])
__global__ __launch_bounds__(128) void k_feat(const float* __restrict__ X,
                                              const float* __restrict__ W,
                                              float* __restrict__ F) {
    __shared__ float sX[BN][FIN];
    const int t = threadIdx.x;               // output column
    const int nbase = blockIdx.x * BN;
    for (int i = t; i < BN * FIN; i += 128) {
        int r = i >> 7, c = i & 127;
        int n = nbase + r;
        sX[r][c] = (n < NN) ? X[n * FIN + c] : 0.f;
    }
    __syncthreads();
    float acc[BN];
#pragma unroll
    for (int i = 0; i < BN; i++) acc[i] = 0.f;
    for (int f = 0; f < FIN; f++) {
        float w = W[f * HD + t];
#pragma unroll
        for (int i = 0; i < BN; i++) acc[i] += sX[i][f] * w;
    }
#pragma unroll
    for (int i = 0; i < BN; i++) {
        int n = nbase + i;
        if (n < NN) F[n * HD + t] = acc[i];
    }
}

// el[n,h] = <feat[n,h,:], al[h,:]> ; er likewise (float4)
__global__ void k_elr(const float* __restrict__ F, const float* __restrict__ al,
                      const float* __restrict__ ar, float* __restrict__ el,
                      float* __restrict__ er, int H, int D) {
    int idx = blockIdx.x * blockDim.x + threadIdx.x;  // n*H + h
    if (idx >= NN * H) return;
    int n = idx / H, h = idx % H;
    const float4* fr = (const float4*)(F + (size_t)n * HD + h * D);
    const float4* alr = (const float4*)(al + h * D);
    const float4* arr = (const float4*)(ar + h * D);
    float sl = 0.f, sr = 0.f;
    for (int q = 0; q < D / 4; q++) {
        float4 v = fr[q], A = alr[q], B = arr[q];
        sl += v.x * A.x + v.y * A.y + v.z * A.z + v.w * A.w;
        sr += v.x * B.x + v.y * B.y + v.z * B.z + v.w * B.w;
    }
    el[idx] = sl;
    er[idx] = sr;
}

// scores in dst-sorted order: esc[i*H+h] = leaky(el[ssrc[i]]+er[sdst[i]]+EF[eperm[i]]@M)
__global__ void k_score(const float* __restrict__ EFt, const int* __restrict__ eperm,
                        const int* __restrict__ ssrc, const int* __restrict__ sdst,
                        const float* __restrict__ el, const float* __restrict__ er,
                        const float* __restrict__ M, float* __restrict__ esc, int H) {
    __shared__ float sM[EF_DIM * 4];
    int t = threadIdx.x;
    if (t < EF_DIM * H) sM[t] = M[t];
    __syncthreads();
    int i = blockIdx.x * blockDim.x + t;
    if (i >= NE) return;
    int e = eperm[i];
    float ef[EF_DIM];
    const float4* efp = (const float4*)(EFt + (size_t)e * EF_DIM);
#pragma unroll
    for (int q = 0; q < 4; q++) {
        float4 v = efp[q];
        ef[4 * q] = v.x; ef[4 * q + 1] = v.y; ef[4 * q + 2] = v.z; ef[4 * q + 3] = v.w;
    }
    int s = ssrc[i], d = sdst[i];
    if (H == 4) {
        float4 l4 = ((const float4*)el)[s];
        float4 r4 = ((const float4*)er)[d];
        float base[4] = {l4.x + r4.x, l4.y + r4.y, l4.z + r4.z, l4.w + r4.w};
        float o[4];
#pragma unroll
        for (int h = 0; h < 4; h++) {
            float ee = 0.f;
#pragma unroll
            for (int f = 0; f < EF_DIM; f++) ee += ef[f] * sM[f * 4 + h];
            float x = base[h] + ee;
            o[h] = (x > 0.f) ? x : 0.2f * x;
        }
        ((float4*)esc)[i] = make_float4(o[0], o[1], o[2], o[3]);
    } else {
        float ee = 0.f;
#pragma unroll
        for (int f = 0; f < EF_DIM; f++) ee += ef[f] * sM[f];
        float x = el[s] + er[d] + ee;
        esc[i] = (x > 0.f) ? x : 0.2f * x;
    }
}

// fused per-dst-node softmax + aggregation: one WAVE per node, 4 waves/block.
// Writes exp() back into esc during the sum pass; aggregate pass reads weights.
__global__ __launch_bounds__(256) void k_node(const int* __restrict__ row_ptr,
                                              const int* __restrict__ ssrc,
                                              float* __restrict__ esc,
                                              const float* __restrict__ F,
                                              const float* __restrict__ b,
                                              float* __restrict__ R,
                                              int H, int D, int act) {
    const int wave = threadIdx.x >> 6;
    const int lane = threadIdx.x & 63;
    const int n = blockIdx.x * 4 + wave;
    if (n >= NN) return;
    const int start = row_ptr[n];
    const int end = row_ptr[n + 1];
    const int c0 = lane, c1 = lane + 64;
    const int h0 = c0 / D, h1 = c1 / D;
    const float b0 = b[c0], b1 = b[c1];

    if (start == end) {
        float v0 = b0, v1 = b1;
        if (act) { v0 = fmaxf(v0, 0.f); v1 = fmaxf(v1, 0.f); }
        R[(size_t)n * HD + c0] = v0;
        R[(size_t)n * HD + c1] = v1;
        return;
    }

    // pass 1: per-head max. element j has head j%H == lane%H (H divides 64).
    float pmax = -3.0e38f;
    for (int j = start * H + lane; j < end * H; j += 64) pmax = fmaxf(pmax, esc[j]);
    for (int m = H; m < 64; m <<= 1) pmax = fmaxf(pmax, __shfl_xor(pmax, m));
    // every lane now holds the max for head (lane % H); lane h (h<H) holds head h.

    // pass 2: sum of exp; write exp back into esc.
    float psum = 0.f;
    for (int j = start * H + lane; j < end * H; j += 64) {
        float ex = __expf(esc[j] - pmax);
        esc[j] = ex;
        psum += ex;
    }
    for (int m = H; m < 64; m <<= 1) psum += __shfl_xor(psum, m);
    const float inv0 = 1.f / __shfl(psum, h0);
    const float inv1 = 1.f / __shfl(psum, h1);

    // pass 3: aggregate
    float a0 = 0.f, a1 = 0.f;
#pragma unroll 4
    for (int i = start; i < end; i++) {
        int sn = ssrc[i];
        const float* Fr = F + (size_t)sn * HD;
        float w0 = esc[(size_t)i * H + h0];
        float w1 = esc[(size_t)i * H + h1];
        a0 += Fr[c0] * w0;
        a1 += Fr[c1] * w1;
    }
    float v0 = a0 * inv0 + b0;
    float v1 = a1 * inv1 + b1;
    if (act) { v0 = fmaxf(v0, 0.f); v1 = fmaxf(v1, 0.f); }
    R[(size_t)n * HD + c0] = v0;
    R[(size_t)n * HD + c1] = v1;
}

// ============================ driver ============================

static void run_layer(const float* X, const float* EFt, const int* eperm,
                      const int* ssrc, const int* sdst, const int* row_ptr,
                      const float* W, const float* al, const float* ar,
                      const float* b, const float* M, int H, int D, int act,
                      float* featbuf, float* esc, float* el, float* er,
                      float* out, hipStream_t stream) {
    const int NH = NN * H;
    hipLaunchKernelGGL(k_feat, dim3((NN + BN - 1) / BN), dim3(128), 0, stream, X, W, featbuf);
    hipLaunchKernelGGL(k_elr, dim3((NH + 255) / 256), dim3(256), 0, stream,
                       featbuf, al, ar, el, er, H, D);
    hipLaunchKernelGGL(k_score, dim3((NE + 255) / 256), dim3(256), 0, stream,
                       EFt, eperm, ssrc, sdst, el, er, M, esc, H);
    hipLaunchKernelGGL(k_node, dim3((NN + 3) / 4), dim3(256), 0, stream,
                       row_ptr, ssrc, esc, featbuf, b, out, H, D, act);
}

extern "C" void kernel_launch(void* const* d_in, const int* in_sizes, int n_in,
                              void* d_out, int out_size, void* d_ws, size_t ws_size,
                              hipStream_t stream) {
    const float* h   = (const float*)d_in[0];
    const float* eft = (const float*)d_in[1];
    const int* src   = (const int*)d_in[2];
    const int* dst   = (const int*)d_in[3];
    auto P = [&](int i) { return (const float*)d_in[i]; };

    float* ws = (float*)d_ws;
    float* featbuf = ws;                            // 6.4M floats
    float* bufA    = featbuf + (size_t)NN * HD;     // 6.4M
    float* esc     = bufA + (size_t)NN * HD;        // 3.2M
    float* el      = esc + (size_t)NE * 4;          // 0.2M
    float* er      = el + (size_t)NN * 4;           // 0.2M
    float* M       = er + (size_t)NN * 4;           // 192
    int* row_ptr   = (int*)(M + 192);               // NN+1
    int* cursor    = row_ptr + (NN + 1);            // NN
    int* deg       = cursor + NN;                   // NN
    int* part      = deg + NN;                      // NPARTS
    int* eperm     = part + NPARTS;                 // NE
    int* ssrc      = eperm + NE;                    // NE
    int* sdst      = ssrc + NE;                     // NE
    float* out     = (float*)d_out;

    // ---- build CSR by dst (once; graph shared by all 3 layers) ----
    hipMemsetAsync(deg, 0, NN * sizeof(int), stream);
    hipLaunchKernelGGL(k_hist, dim3((NE + 255) / 256), dim3(256), 0, stream, dst, deg);
    hipLaunchKernelGGL(k_part, dim3(NPARTS), dim3(SCAN_B), 0, stream, deg, part);
    hipLaunchKernelGGL(k_scanpart, dim3(1), dim3(SCAN_B), 0, stream, part);
    hipLaunchKernelGGL(k_rowptr, dim3(NPARTS), dim3(SCAN_B), 0, stream,
                       deg, part, row_ptr, cursor);
    hipLaunchKernelGGL(k_scatter, dim3((NE + 255) / 256), dim3(256), 0, stream,
                       src, dst, cursor, eperm, ssrc, sdst);
    hipLaunchKernelGGL(k_M3, dim3(3), dim3(64), 0, stream,
                       P(5), P(8), P(11), P(14), P(17), P(20), M);

    // layer 0: h -> bufA (H=4, D=32, relu)
    run_layer(h, eft, eperm, ssrc, sdst, row_ptr, P(4), P(6), P(7), P(9), M,
              4, 32, 1, featbuf, esc, el, er, bufA, stream);
    // layer 1: bufA -> bufA (in-place safe: bufA read only by k_feat, first kernel)
    run_layer(bufA, eft, eperm, ssrc, sdst, row_ptr, P(10), P(12), P(13), P(15), M + 64,
              4, 32, 1, featbuf, esc, el, er, bufA, stream);
    // layer 2: bufA -> out (H=1, D=128, no act)
    run_layer(bufA, eft, eperm, ssrc, sdst, row_ptr, P(16), P(18), P(19), P(21), M + 128,
              1, 128, 0, featbuf, esc, el, er, out, stream);
}